// Round 2
// baseline (454.915 us; speedup 1.0000x reference)
//
#include <hip/hip_runtime.h>

#define DEVI __device__ __forceinline__

typedef __attribute__((ext_vector_type(8))) short short8;
typedef __attribute__((ext_vector_type(4))) float f32x4;

#define ATTN_SCALE 0.10206207261596575f  // 96^-0.5

DEVI unsigned short f2bf(float f){
  unsigned u = __float_as_uint(f);
  u += 0x7fff + ((u >> 16) & 1);          // RNE
  return (unsigned short)(u >> 16);
}
DEVI float bf2f(unsigned short h){ return __uint_as_float(((unsigned)h) << 16); }

DEVI void gload16(const void* g, void* l){
  __builtin_amdgcn_global_load_lds((const __attribute__((address_space(1))) void*)g,
                                   (__attribute__((address_space(3))) void*)l, 16, 0, 0);
}

DEVI f32x4 mfma16(short8 a, short8 b, f32x4 c){
  return __builtin_amdgcn_mfma_f32_16x16x32_bf16(a, b, c, 0, 0, 0);
}

// ---------------- K1: f32 -> bf16 convert (hidden), convert+transpose (qkv_w) ---
__global__ __launch_bounds__(256) void k_convert(const float4* __restrict__ hs4,
    const float* __restrict__ w, unsigned short* __restrict__ hsb,
    unsigned short* __restrict__ wt){
  const int stride = gridDim.x * 256;
  const int t0 = blockIdx.x * 256 + threadIdx.x;
  const int n4 = (50176 * 192) / 4;
  for (int i = t0; i < n4; i += stride){
    float4 v = hs4[i];
    uint2 p;
    p.x = (unsigned)f2bf(v.x) | ((unsigned)f2bf(v.y) << 16);
    p.y = (unsigned)f2bf(v.z) | ((unsigned)f2bf(v.w) << 16);
    ((uint2*)hsb)[i] = p;
  }
  for (int i = t0; i < 192 * 1152; i += stride){
    int k = i / 1152, n = i - k * 1152;
    wt[n * 192 + k] = f2bf(w[i]);
  }
}

// ---------------- K2: QKV GEMM  C[50176,1152] = A[50176,192] * W[192,1152] + b --
// Double-buffered staging (1 barrier/kk), XCD-swizzled block order.
__global__ __launch_bounds__(256) void k_gemm(const unsigned short* __restrict__ A,
    const unsigned short* __restrict__ Bt,   // [1152][192] (pre-transposed, K-major)
    const float* __restrict__ bias, unsigned short* __restrict__ C){
  __shared__ unsigned short sA[2][128 * 64];
  __shared__ unsigned short sB[2][128 * 64];
  // bijective XCD swizzle: 3528 = 8 * 441
  const int bid = (blockIdx.x & 7) * 441 + (blockIdx.x >> 3);
  const int bn = bid % 9, bm = bid / 9;
  const int tid = threadIdx.x, w = tid >> 6, l = tid & 63;
  const int wr = (w >> 1) * 64, wc = (w & 1) * 64;
  const int l15 = l & 15, l4 = l >> 4;
  const f32x4 z4 = {0.f, 0.f, 0.f, 0.f};
  f32x4 acc[4][4];
#pragma unroll
  for (int i = 0; i < 4; ++i)
#pragma unroll
    for (int j = 0; j < 4; ++j) acc[i][j] = z4;

  auto stage = [&](int kk, int buf){
    const int k0 = kk * 64;
#pragma unroll
    for (int i = 0; i < 4; ++i){
      const int ib = (w * 4 + i) << 10;
      const int Lb = ib + (l << 4);
      const int r  = Lb >> 7;                       // LDS row (128B rows)
      const int g  = ((Lb >> 4) & 7) ^ (r & 7);     // pre-swizzled source granule
      gload16((const char*)A  + (size_t)(bm * 128 + r) * 384 + k0 * 2 + g * 16, (char*)sA[buf] + ib);
      gload16((const char*)Bt + (size_t)(bn * 128 + r) * 384 + k0 * 2 + g * 16, (char*)sB[buf] + ib);
    }
  };

  stage(0, 0);
  __syncthreads();
  for (int kk = 0; kk < 3; ++kk){
    const int buf = kk & 1;
    if (kk < 2) stage(kk + 1, buf ^ 1);
#pragma unroll
    for (int ks = 0; ks < 2; ++ks){
      short8 av[4], bv[4];
#pragma unroll
      for (int mf = 0; mf < 4; ++mf){
        const int r = wr + mf * 16 + l15;
        const int slot = (ks * 4 + l4) ^ (r & 7);
        av[mf] = *(const short8*)(sA[buf] + r * 64 + slot * 8);
      }
#pragma unroll
      for (int nf = 0; nf < 4; ++nf){
        const int r = wc + nf * 16 + l15;
        const int slot = (ks * 4 + l4) ^ (r & 7);
        bv[nf] = *(const short8*)(sB[buf] + r * 64 + slot * 8);
      }
#pragma unroll
      for (int mf = 0; mf < 4; ++mf)
#pragma unroll
        for (int nf = 0; nf < 4; ++nf)
          acc[mf][nf] = mfma16(av[mf], bv[nf], acc[mf][nf]);
    }
    if (kk < 2) __syncthreads();
  }
#pragma unroll
  for (int nf = 0; nf < 4; ++nf){
    const int col = bn * 128 + wc + nf * 16 + l15;
    const float bv = bias[col];
#pragma unroll
    for (int mf = 0; mf < 4; ++mf)
#pragma unroll
      for (int reg = 0; reg < 4; ++reg){
        const int row = bm * 128 + wr + mf * 16 + l4 * 4 + reg;
        C[(size_t)row * 1152 + col] = f2bf(acc[mf][nf][reg] + bv);
      }
  }
}

// ---------------- K3: depthwise 3x3 s2 pool + LayerNorm ------------------------
// qp additionally carries ATTN_SCALE folded in (attn Q-frag input only).
__global__ __launch_bounds__(256) void k_pool_ln(const unsigned short* __restrict__ qkv,
    const float* __restrict__ wq, const float* __restrict__ wk, const float* __restrict__ wv,
    const float* __restrict__ gq, const float* __restrict__ bq,
    const float* __restrict__ gk, const float* __restrict__ bk,
    const float* __restrict__ gv, const float* __restrict__ bv,
    unsigned short* __restrict__ qp, unsigned short* __restrict__ kp,
    unsigned short* __restrict__ vpt, float* __restrict__ qpf){
  __shared__ float sw[864];
  __shared__ float sg[96], sb[96];
  __shared__ float sbuf[28 * 96];
  const int bid = blockIdx.x;
  const int oy = bid % 28, h = (bid / 28) & 3, b = (bid / 112) & 15, which = bid / 1792;
  const float* wsel = which == 0 ? wq : (which == 1 ? wk : wv);
  const float* gsel = which == 0 ? gq : (which == 1 ? gk : gv);
  const float* bsel = which == 0 ? bq : (which == 1 ? bk : bv);
  const int tid = threadIdx.x;
  for (int i = tid; i < 864; i += 256) sw[i] = wsel[i];
  if (tid < 96){ sg[tid] = gsel[tid]; sb[tid] = bsel[tid]; }
  __syncthreads();
  const int colbase = which * 384 + h * 96;
  for (int item = tid; item < 2688; item += 256){
    const int ox = item / 96, d = item - ox * 96;
    float acc = 0.f;
#pragma unroll
    for (int ky = 0; ky < 3; ++ky){
      const int iy = oy * 2 + ky - 1;
      if ((unsigned)iy >= 56u) continue;
      const unsigned short* rowp = qkv + (size_t)(b * 3136 + iy * 56) * 1152 + colbase + d;
#pragma unroll
      for (int kx = 0; kx < 3; ++kx){
        const int ix = ox * 2 + kx - 1;
        if ((unsigned)ix >= 56u) continue;
        acc += bf2f(rowp[(size_t)ix * 1152]) * sw[d * 9 + ky * 3 + kx];
      }
    }
    sbuf[ox * 96 + d] = acc;
  }
  __syncthreads();
  const int wv_ = tid >> 6, l = tid & 63;
  const size_t bh = (size_t)(b * 4 + h);
  for (int oxi = 0; oxi < 7; ++oxi){
    const int ox = wv_ * 7 + oxi;
    const float x1 = sbuf[ox * 96 + l];
    const float x2 = (l < 32) ? sbuf[ox * 96 + 64 + l] : 0.f;
    float s = x1 + x2, ss = x1 * x1 + x2 * x2;
#pragma unroll
    for (int d = 1; d < 64; d <<= 1){ s += __shfl_xor(s, d); ss += __shfl_xor(ss, d); }
    const float mean = s * (1.f / 96.f);
    const float var  = ss * (1.f / 96.f) - mean * mean;
    const float rstd = rsqrtf(var + 1e-6f);
    const int n = oy * 28 + ox;
    {
      const float y = (x1 - mean) * rstd * sg[l] + sb[l];
      if (which == 0){ const size_t idx = (bh * 784 + n) * 96 + l; qp[idx] = f2bf(y * ATTN_SCALE); qpf[idx] = y; }
      else if (which == 1){ kp[(bh * 784 + n) * 96 + l] = f2bf(y); }
      else { vpt[(bh * 96 + l) * 784 + n] = f2bf(y); }
    }
    if (l < 32){
      const int d = 64 + l;
      const float y = (x2 - mean) * rstd * sg[d] + sb[d];
      if (which == 0){ const size_t idx = (bh * 784 + n) * 96 + d; qp[idx] = f2bf(y * ATTN_SCALE); qpf[idx] = y; }
      else if (which == 1){ kp[(bh * 784 + n) * 96 + d] = f2bf(y); }
      else { vpt[(bh * 96 + d) * 784 + n] = f2bf(y); }
    }
  }
}

// ---------------- K4: fused attention (flash-style, rel-pos, residual) ---------
// Q frags in registers; K double-buffered via global_load_lds issued at loop top;
// V reg-staged (issue-early / ds_write-late); P overlaid into the consumed K buf.
__global__ __launch_bounds__(256, 3) void k_attn(
    const unsigned short* __restrict__ qp, const unsigned short* __restrict__ kp,
    const unsigned short* __restrict__ vpt, const float* __restrict__ qpf,
    const float* __restrict__ relh, const float* __restrict__ relw,
    float* __restrict__ out){
  __shared__ unsigned short sK[2][64 * 128];   // 2 x 16KB, 256B rows, XOR-swizzled granules
  __shared__ unsigned short sV[96 * 64];       // V^T tile [d][key], 128B rows, 12KB
  __shared__ unsigned short sEh[64 * 28];      // rel-pos tables, bf16
  __shared__ unsigned short sEw[64 * 28];
  const int qt = blockIdx.x % 13, bh = blockIdx.x / 13;
  const int b = bh >> 2, h = bh & 3;
  const int tid = threadIdx.x, w = tid >> 6, l = tid & 63;
  const int l15 = l & 15, l4 = l >> 4;
  const size_t base = (size_t)bh * 784 * 96;
  const f32x4 z4 = {0.f, 0.f, 0.f, 0.f};

  // ---- K staging: global_load_lds into sK[buf] (pre-swizzled source) ----
  auto stageK = [&](int t, int buf){
#pragma unroll
    for (int i = 0; i < 4; ++i){
      const int ib = (w * 4 + i) << 10;
      const int Lb = ib + (l << 4);
      const int r = Lb >> 8;                         // 256B rows
      const int g = ((Lb >> 4) & 15) ^ (r & 7);
      int kr = t * 64 + r; if (kr > 783) kr = 783;
      const size_t gb = (base + (size_t)kr * 96) * 2 + (g < 12 ? g * 16 : 0);
      gload16((const char*)kp + gb, (char*)sK[buf] + ib);
    }
  };
  // ---- V staging: global -> regs (issue-early), ds_write later ----
  short8 vreg[3];
  auto loadV = [&](int t){
#pragma unroll
    for (int i = 0; i < 3; ++i){
      const int off = ((w * 3 + i) << 10) + (l << 4);
      const int r = off >> 7;                        // d row (128B rows)
      const int g = ((off >> 4) & 7) ^ (r & 7);
      int koff = t * 64 + g * 8; if (koff + 8 > 784) koff = 0;  // masked via P=0
      vreg[i] = *(const short8*)(vpt + (size_t)(bh * 96 + r) * 784 + koff);
    }
  };
  auto writeV = [&](){
#pragma unroll
    for (int i = 0; i < 3; ++i){
      const int off = ((w * 3 + i) << 10) + (l << 4);
      *(short8*)((char*)sV + off) = vreg[i];
    }
  };

  // issue tile-0 staging first so its latency hides under the rel-pos prologue
  stageK(0, 0);
  loadV(0);

  // ---- Q fragments in registers (lane: row = qt*64 + w*16 + l15) ----
  short8 qf[3];
  {
    int qr = qt * 64 + w * 16 + l15; if (qr > 783) qr = 783;
#pragma unroll
    for (int ks = 0; ks < 3; ++ks)
      qf[ks] = *(const short8*)(qp + base + (size_t)qr * 96 + ks * 32 + l4 * 8);
  }

  // ---- Eh/Ew tables: dot(q_row, rel_h[hh-kh+27]) / dot(q_row, rel_w[ww-kw+27]) --
  for (int item = tid; item < 64 * 56; item += 256){
    const int r = item & 63, e = item >> 6;
    int qr = qt * 64 + r; if (qr > 783) qr = 783;
    const int hh = qr / 28, ww = qr - hh * 28;
    const float* qv = qpf + base + (size_t)qr * 96;
    const float* rv = (e < 28) ? (relh + (hh - e + 27) * 96)
                               : (relw + (ww - (e - 28) + 27) * 96);
    float acc = 0.f;
#pragma unroll
    for (int d = 0; d < 96; d += 4){
      const float4 a = *(const float4*)(qv + d);
      const float4 c = *(const float4*)(rv + d);
      acc += a.x * c.x + a.y * c.y + a.z * c.z + a.w * c.w;
    }
    if (e < 28) sEh[r * 28 + e] = f2bf(acc); else sEw[r * 28 + e - 28] = f2bf(acc);
  }

  float m_reg[4], l_reg[4];
#pragma unroll
  for (int i = 0; i < 4; ++i){ m_reg[i] = -1e30f; l_reg[i] = 0.f; }
  f32x4 acc_o[6];
#pragma unroll
  for (int i = 0; i < 6; ++i) acc_o[i] = z4;

  writeV();            // waits vmcnt on vreg internally
  __syncthreads();     // drains K(0) gload_lds; sV + sE visible

  for (int kt = 0; kt < 13; ++kt){
    const int cur = kt & 1;
    if (kt < 12){ loadV(kt + 1); stageK(kt + 1, cur ^ 1); }

    // ---- S = Q K^T (wave w owns q rows 16w..16w+15) ----
    f32x4 sfr[4];
#pragma unroll
    for (int i = 0; i < 4; ++i) sfr[i] = z4;
#pragma unroll
    for (int ks = 0; ks < 3; ++ks){
#pragma unroll
      for (int nf = 0; nf < 4; ++nf){
        const int rb = nf * 16 + l15;
        const int sb2 = (ks * 4 + l4) ^ (rb & 7);
        const short8 bb = *(const short8*)(sK[cur] + rb * 128 + sb2 * 8);
        sfr[nf] = mfma16(qf[ks], bb, sfr[nf]);
      }
    }

    // ---- online softmax in fragment layout (row = w*16 + 4*l4 + reg, col = l15) --
    float pvv[4][4];
    float rmax[4] = {-1e30f, -1e30f, -1e30f, -1e30f};
    const int rbase = w * 16 + l4 * 4;
#pragma unroll
    for (int nf = 0; nf < 4; ++nf){
      const int kidx = kt * 64 + nf * 16 + l15;
      const bool valid = kidx < 784;
      const int kc = valid ? kidx : 0;
      const int kh = (kc * 2341) >> 16;            // /28
      const int kw2 = kc - kh * 28;
#pragma unroll
      for (int reg = 0; reg < 4; ++reg){
        const int rl = rbase + reg;
        const float sv = valid ? (sfr[nf][reg] + bf2f(sEh[rl * 28 + kh]) + bf2f(sEw[rl * 28 + kw2]))
                               : -1e30f;
        pvv[nf][reg] = sv;
        rmax[reg] = fmaxf(rmax[reg], sv);
      }
    }
#pragma unroll
    for (int s = 1; s < 16; s <<= 1)
#pragma unroll
      for (int reg = 0; reg < 4; ++reg)
        rmax[reg] = fmaxf(rmax[reg], __shfl_xor(rmax[reg], s));
    float alpha[4], rsum[4];
#pragma unroll
    for (int reg = 0; reg < 4; ++reg){
      const float mn = fmaxf(m_reg[reg], rmax[reg]);
      alpha[reg] = __expf(m_reg[reg] - mn);
      m_reg[reg] = mn;
      rsum[reg] = 0.f;
    }
#pragma unroll
    for (int nf = 0; nf < 4; ++nf)
#pragma unroll
      for (int reg = 0; reg < 4; ++reg){
        const float p = __expf(pvv[nf][reg] - m_reg[reg]);
        pvv[nf][reg] = p;
        rsum[reg] += p;
      }
#pragma unroll
    for (int s = 1; s < 16; s <<= 1)
#pragma unroll
      for (int reg = 0; reg < 4; ++reg)
        rsum[reg] += __shfl_xor(rsum[reg], s);
#pragma unroll
    for (int reg = 0; reg < 4; ++reg)
      l_reg[reg] = l_reg[reg] * alpha[reg] + rsum[reg];

    __syncthreads();   // B1: all QK^T reads of sK[cur] done -> its head is free for P

    // ---- P into sK[cur][0:8KB]; intra-wave rows only (no barrier needed) ----
    unsigned short* sPp = sK[cur];
#pragma unroll
    for (int nf = 0; nf < 4; ++nf)
#pragma unroll
      for (int reg = 0; reg < 4; ++reg){
        const int rl = rbase + reg;
        const int c = nf * 16 + l15;
        const int slot = (c >> 3) ^ (rl & 7);
        sPp[rl * 64 + slot * 8 + (c & 7)] = f2bf(pvv[nf][reg]);
      }
    // rescale O
#pragma unroll
    for (int i = 0; i < 6; ++i)
#pragma unroll
      for (int reg = 0; reg < 4; ++reg)
        acc_o[i][reg] *= alpha[reg];
    // ---- O += P V ----
#pragma unroll
    for (int ks = 0; ks < 2; ++ks){
      const int ra = w * 16 + l15;
      const int sa = (ks * 4 + l4) ^ (ra & 7);
      const short8 a = *(const short8*)(sPp + ra * 64 + sa * 8);
#pragma unroll
      for (int nf = 0; nf < 6; ++nf){
        const int rv_ = nf * 16 + l15;
        const int sv2 = (ks * 4 + l4) ^ (rv_ & 7);
        const short8 bb = *(const short8*)(sV + rv_ * 64 + sv2 * 8);
        acc_o[nf] = mfma16(a, bb, acc_o[nf]);
      }
    }
    __syncthreads();   // B2: PV done (sV free), K(t+1) staging drained
    if (kt < 12) writeV();
  }

  // ---- epilogue: normalize, add residual q, write [B,784,384] ----
#pragma unroll
  for (int nf = 0; nf < 6; ++nf){
    const int d = nf * 16 + l15;
#pragma unroll
    for (int reg = 0; reg < 4; ++reg){
      const int rl = w * 16 + l4 * 4 + reg;
      const int qr = qt * 64 + rl;
      if (qr < 784){
        const float v = acc_o[nf][reg] / l_reg[reg] + qpf[base + (size_t)qr * 96 + d];
        out[((size_t)b * 784 + qr) * 384 + h * 96 + d] = v;
      }
    }
  }
}

// ---------------- launcher -----------------------------------------------------
extern "C" void kernel_launch(void* const* d_in, const int* in_sizes, int n_in,
                              void* d_out, int out_size, void* d_ws, size_t ws_size,
                              hipStream_t stream){
  const float* hs  = (const float*)d_in[0];
  const float* qw  = (const float*)d_in[1];
  const float* qb  = (const float*)d_in[2];
  const float* pwq = (const float*)d_in[3];
  const float* pwk = (const float*)d_in[4];
  const float* pwv = (const float*)d_in[5];
  const float* gq  = (const float*)d_in[6];
  const float* bq  = (const float*)d_in[7];
  const float* gk  = (const float*)d_in[8];
  const float* bk  = (const float*)d_in[9];
  const float* gv  = (const float*)d_in[10];
  const float* bv  = (const float*)d_in[11];
  const float* rh  = (const float*)d_in[12];
  const float* rw  = (const float*)d_in[13];
  float* out = (float*)d_out;

  char* ws = (char*)d_ws;
  size_t off = 0;
  auto take = [&](size_t n)->char*{ char* p = ws + off; off += (n + 255) & ~(size_t)255; return p; };
  unsigned short* hsb = (unsigned short*)take((size_t)50176 * 192 * 2);
  unsigned short* wtb = (unsigned short*)take((size_t)1152 * 192 * 2);
  unsigned short* qkv = (unsigned short*)take((size_t)50176 * 1152 * 2);
  unsigned short* qpb = (unsigned short*)take((size_t)64 * 784 * 96 * 2);
  unsigned short* kpb = (unsigned short*)take((size_t)64 * 784 * 96 * 2);
  unsigned short* vpt = (unsigned short*)take((size_t)64 * 784 * 96 * 2);
  float* qpf          = (float*)take((size_t)64 * 784 * 96 * 4);

  hipLaunchKernelGGL(k_convert, dim3(1024), dim3(256), 0, stream,
                     (const float4*)hs, qw, hsb, wtb);
  hipLaunchKernelGGL(k_gemm, dim3(392 * 9), dim3(256), 0, stream, hsb, wtb, qb, qkv);
  hipLaunchKernelGGL(k_pool_ln, dim3(5376), dim3(256), 0, stream, qkv,
                     pwq, pwk, pwv, gq, bq, gk, bk, gv, bv, qpb, kpb, vpt, qpf);
  hipLaunchKernelGGL(k_attn, dim3(64 * 13), dim3(256), 0, stream,
                     qpb, kpb, vpt, qpf, rh, rw, out);
}

// Round 3
// 320.528 us; speedup vs baseline: 1.4193x; 1.4193x over previous
//
#include <hip/hip_runtime.h>

#define DEVI __device__ __forceinline__

typedef __attribute__((ext_vector_type(8))) short short8;
typedef __attribute__((ext_vector_type(4))) short short4v;
typedef __attribute__((ext_vector_type(4))) float f32x4;

#define ATTN_SCALE 0.10206207261596575f  // 96^-0.5

DEVI unsigned short f2bf(float f){
  unsigned u = __float_as_uint(f);
  u += 0x7fff + ((u >> 16) & 1);          // RNE
  return (unsigned short)(u >> 16);
}
DEVI float bf2f(unsigned short h){ return __uint_as_float(((unsigned)h) << 16); }

DEVI void gload16(const void* g, void* l){
  __builtin_amdgcn_global_load_lds((const __attribute__((address_space(1))) void*)g,
                                   (__attribute__((address_space(3))) void*)l, 16, 0, 0);
}

DEVI f32x4 mfma16(short8 a, short8 b, f32x4 c){
  return __builtin_amdgcn_mfma_f32_16x16x32_bf16(a, b, c, 0, 0, 0);
}

DEVI short8 pack_bf8(const float* p){   // 8 consecutive f32 -> bf16 x8
  float4 a = *(const float4*)p, b = *(const float4*)(p + 4);
  short8 r;
  r[0] = f2bf(a.x); r[1] = f2bf(a.y); r[2] = f2bf(a.z); r[3] = f2bf(a.w);
  r[4] = f2bf(b.x); r[5] = f2bf(b.y); r[6] = f2bf(b.z); r[7] = f2bf(b.w);
  return r;
}

// ---------------- K1: f32 -> bf16 convert (hidden), convert+transpose (qkv_w) ---
__global__ __launch_bounds__(256) void k_convert(const float4* __restrict__ hs4,
    const float* __restrict__ w, unsigned short* __restrict__ hsb,
    unsigned short* __restrict__ wt){
  const int stride = gridDim.x * 256;
  const int t0 = blockIdx.x * 256 + threadIdx.x;
  const int n4 = (50176 * 192) / 4;
  for (int i = t0; i < n4; i += stride){
    float4 v = hs4[i];
    uint2 p;
    p.x = (unsigned)f2bf(v.x) | ((unsigned)f2bf(v.y) << 16);
    p.y = (unsigned)f2bf(v.z) | ((unsigned)f2bf(v.w) << 16);
    ((uint2*)hsb)[i] = p;
  }
  for (int i = t0; i < 192 * 1152; i += stride){
    int k = i / 1152, n = i - k * 1152;
    wt[n * 192 + k] = f2bf(w[i]);
  }
}

// ---------------- K2: QKV GEMM  C[50176,1152] = A[50176,192] * W[192,1152] + b --
__global__ __launch_bounds__(256) void k_gemm(const unsigned short* __restrict__ A,
    const unsigned short* __restrict__ Bt,   // [1152][192] (pre-transposed, K-major)
    const float* __restrict__ bias, unsigned short* __restrict__ C){
  __shared__ unsigned short sA[2][128 * 64];
  __shared__ unsigned short sB[2][128 * 64];
  // bijective XCD swizzle: 3528 = 8 * 441
  const int bid = (blockIdx.x & 7) * 441 + (blockIdx.x >> 3);
  const int bn = bid % 9, bm = bid / 9;
  const int tid = threadIdx.x, w = tid >> 6, l = tid & 63;
  const int wr = (w >> 1) * 64, wc = (w & 1) * 64;
  const int l15 = l & 15, l4 = l >> 4;
  const f32x4 z4 = {0.f, 0.f, 0.f, 0.f};
  f32x4 acc[4][4];
#pragma unroll
  for (int i = 0; i < 4; ++i)
#pragma unroll
    for (int j = 0; j < 4; ++j) acc[i][j] = z4;

  auto stage = [&](int kk, int buf){
    const int k0 = kk * 64;
#pragma unroll
    for (int i = 0; i < 4; ++i){
      const int ib = (w * 4 + i) << 10;
      const int Lb = ib + (l << 4);
      const int r  = Lb >> 7;
      const int g  = ((Lb >> 4) & 7) ^ (r & 7);
      gload16((const char*)A  + (size_t)(bm * 128 + r) * 384 + k0 * 2 + g * 16, (char*)sA[buf] + ib);
      gload16((const char*)Bt + (size_t)(bn * 128 + r) * 384 + k0 * 2 + g * 16, (char*)sB[buf] + ib);
    }
  };

  stage(0, 0);
  __syncthreads();
  for (int kk = 0; kk < 3; ++kk){
    const int buf = kk & 1;
    if (kk < 2) stage(kk + 1, buf ^ 1);
#pragma unroll
    for (int ks = 0; ks < 2; ++ks){
      short8 av[4], bv[4];
#pragma unroll
      for (int mf = 0; mf < 4; ++mf){
        const int r = wr + mf * 16 + l15;
        const int slot = (ks * 4 + l4) ^ (r & 7);
        av[mf] = *(const short8*)(sA[buf] + r * 64 + slot * 8);
      }
#pragma unroll
      for (int nf = 0; nf < 4; ++nf){
        const int r = wc + nf * 16 + l15;
        const int slot = (ks * 4 + l4) ^ (r & 7);
        bv[nf] = *(const short8*)(sB[buf] + r * 64 + slot * 8);
      }
#pragma unroll
      for (int mf = 0; mf < 4; ++mf)
#pragma unroll
        for (int nf = 0; nf < 4; ++nf)
          acc[mf][nf] = mfma16(av[mf], bv[nf], acc[mf][nf]);
    }
    if (kk < 2) __syncthreads();
  }
#pragma unroll
  for (int nf = 0; nf < 4; ++nf){
    const int col = bn * 128 + wc + nf * 16 + l15;
    const float bv = bias[col];
#pragma unroll
    for (int mf = 0; mf < 4; ++mf)
#pragma unroll
      for (int reg = 0; reg < 4; ++reg){
        const int row = bm * 128 + wr + mf * 16 + l4 * 4 + reg;
        C[(size_t)row * 1152 + col] = f2bf(acc[mf][nf][reg] + bv);
      }
  }
}

// ---------------- K3: depthwise 3x3 s2 pool + LayerNorm ------------------------
// ATTN_SCALE folded into kp (QK^T only); qp stays unscaled (used for G tables + QK).
__global__ __launch_bounds__(256) void k_pool_ln(const unsigned short* __restrict__ qkv,
    const float* __restrict__ wq, const float* __restrict__ wk, const float* __restrict__ wv,
    const float* __restrict__ gq, const float* __restrict__ bq,
    const float* __restrict__ gk, const float* __restrict__ bk,
    const float* __restrict__ gv, const float* __restrict__ bv,
    unsigned short* __restrict__ qp, unsigned short* __restrict__ kp,
    unsigned short* __restrict__ vpt, float* __restrict__ qpf){
  __shared__ float sw[864];
  __shared__ float sg[96], sb[96];
  __shared__ float sbuf[28 * 96];
  const int bid = blockIdx.x;
  const int oy = bid % 28, h = (bid / 28) & 3, b = (bid / 112) & 15, which = bid / 1792;
  const float* wsel = which == 0 ? wq : (which == 1 ? wk : wv);
  const float* gsel = which == 0 ? gq : (which == 1 ? gk : gv);
  const float* bsel = which == 0 ? bq : (which == 1 ? bk : bv);
  const int tid = threadIdx.x;
  for (int i = tid; i < 864; i += 256) sw[i] = wsel[i];
  if (tid < 96){ sg[tid] = gsel[tid]; sb[tid] = bsel[tid]; }
  __syncthreads();
  const int colbase = which * 384 + h * 96;
  for (int item = tid; item < 2688; item += 256){
    const int ox = item / 96, d = item - ox * 96;
    float acc = 0.f;
#pragma unroll
    for (int ky = 0; ky < 3; ++ky){
      const int iy = oy * 2 + ky - 1;
      if ((unsigned)iy >= 56u) continue;
      const unsigned short* rowp = qkv + (size_t)(b * 3136 + iy * 56) * 1152 + colbase + d;
#pragma unroll
      for (int kx = 0; kx < 3; ++kx){
        const int ix = ox * 2 + kx - 1;
        if ((unsigned)ix >= 56u) continue;
        acc += bf2f(rowp[(size_t)ix * 1152]) * sw[d * 9 + ky * 3 + kx];
      }
    }
    sbuf[ox * 96 + d] = acc;
  }
  __syncthreads();
  const int wv_ = tid >> 6, l = tid & 63;
  const size_t bh = (size_t)(b * 4 + h);
  for (int oxi = 0; oxi < 7; ++oxi){
    const int ox = wv_ * 7 + oxi;
    const float x1 = sbuf[ox * 96 + l];
    const float x2 = (l < 32) ? sbuf[ox * 96 + 64 + l] : 0.f;
    float s = x1 + x2, ss = x1 * x1 + x2 * x2;
#pragma unroll
    for (int d = 1; d < 64; d <<= 1){ s += __shfl_xor(s, d); ss += __shfl_xor(ss, d); }
    const float mean = s * (1.f / 96.f);
    const float var  = ss * (1.f / 96.f) - mean * mean;
    const float rstd = rsqrtf(var + 1e-6f);
    const int n = oy * 28 + ox;
    {
      const float y = (x1 - mean) * rstd * sg[l] + sb[l];
      if (which == 0){ const size_t idx = (bh * 784 + n) * 96 + l; qp[idx] = f2bf(y); qpf[idx] = y; }
      else if (which == 1){ kp[(bh * 784 + n) * 96 + l] = f2bf(y * ATTN_SCALE); }
      else { vpt[(bh * 96 + l) * 784 + n] = f2bf(y); }
    }
    if (l < 32){
      const int d = 64 + l;
      const float y = (x2 - mean) * rstd * sg[d] + sb[d];
      if (which == 0){ const size_t idx = (bh * 784 + n) * 96 + d; qp[idx] = f2bf(y); qpf[idx] = y; }
      else if (which == 1){ kp[(bh * 784 + n) * 96 + d] = f2bf(y * ATTN_SCALE); }
      else { vpt[(bh * 96 + d) * 784 + n] = f2bf(y * 1.0f); }
    }
  }
}

// ---------------- K4: fused attention, swapped-operand flash ------------------
// 512 thr, 128 q-rows/block. S^T = mfma(K,Q): softmax is lane-local + 2 shfl.
// Rel-pos tables G computed by MFMA. K dbuf gload_lds; V reg-staged (T14).
__global__ __launch_bounds__(512, 4) void k_attn(
    const unsigned short* __restrict__ qp, const unsigned short* __restrict__ kp,
    const unsigned short* __restrict__ vpt, const float* __restrict__ qpf,
    const float* __restrict__ relh, const float* __restrict__ relw,
    float* __restrict__ out){
  __shared__ unsigned short sK[2][64 * 128];   // 32KB (256B rows, swizzled granules)
  __shared__ unsigned short sV[96 * 64];       // 12KB V^T tile [d][k]
  __shared__ unsigned short sP[128 * 64];      // 16KB P^T-as-[q][k], swizzled
  __shared__ unsigned short sGh[128 * 34];     // 8.5KB, [q_local][kh]
  __shared__ unsigned short sGw[128 * 34];     // 8.5KB, [q_local][kw]

  // XCD mapping: all 7 q-blocks of one bh land on one XCD (K/V L2-resident)
  const int s = blockIdx.x, xcd = s & 7, slot = s >> 3;
  const int bh = xcd * 8 + slot / 7, qb = slot - (slot / 7) * 7;
  const int b = bh >> 2, h = bh & 3;
  const int tid = threadIdx.x, w = tid >> 6, l = tid & 63;
  const int l15 = l & 15, l4 = l >> 4;
  const size_t base = (size_t)bh * 784 * 96;
  const f32x4 z4 = {0.f, 0.f, 0.f, 0.f};
  const int qrl = w * 16 + l15;                 // local q row 0..127
  int q_l = qb * 128 + qrl; if (q_l > 783) q_l = 783;
  const int gbase = qrl * 34;

  auto stageK = [&](int t, int buf){
#pragma unroll
    for (int i = 0; i < 2; ++i){
      const int ib = (w * 2 + i) << 10;
      const int Lb = ib + (l << 4);
      const int r = Lb >> 8;                     // 256B rows
      const int g = ((Lb >> 4) & 15) ^ (r & 7);
      int kr = t * 64 + r; if (kr > 783) kr = 783;
      const size_t gb = (base + (size_t)kr * 96) * 2 + (g < 12 ? g * 16 : 0);
      gload16((const char*)kp + gb, (char*)sK[buf] + ib);
    }
  };
  short8 vreg[2];
  auto loadV = [&](int t){
    if (tid < 384){
#pragma unroll
      for (int i = 0; i < 2; ++i){
        const int off = (tid * 2 + i) << 4;      // bytes in sV
        const int r = off >> 7;                  // d row (128B rows)
        const int g = ((off >> 4) & 7) ^ (r & 7);
        int koff = t * 64 + g * 8; if (koff + 8 > 784) koff = 0;  // masked by P=0
        vreg[i] = *(const short8*)(vpt + (size_t)(bh * 96 + r) * 784 + koff);
      }
    }
  };
  auto writeV = [&](){
    if (tid < 384){
#pragma unroll
      for (int i = 0; i < 2; ++i)
        *(short8*)((char*)sV + ((tid * 2 + i) << 4)) = vreg[i];
    }
  };

  stageK(0, 0);
  loadV(0);

  // Q fragments (B-operand layout): lane holds Q[q_l][d = ks*32 + l4*8 + j]
  short8 qf[3];
#pragma unroll
  for (int ks = 0; ks < 3; ++ks)
    qf[ks] = *(const short8*)(qp + base + (size_t)q_l * 96 + ks * 32 + l4 * 8);

  const int hh = (q_l * 2341) >> 16;             // /28 (exact for <=847)
  const int ww = q_l - hh * 28;
  const int h0 = (qb * 128) / 28;

  // G tables via MFMA: G[j][q] = dot(rel[j], q). Gh window j in [h0,h0+47].
  {
    f32x4 gh[3] = {z4, z4, z4}, gw[4] = {z4, z4, z4, z4};
#pragma unroll
    for (int nf = 0; nf < 3; ++nf){
      int j = h0 + nf * 16 + l15; if (j > 54) j = 54;
#pragma unroll
      for (int ks = 0; ks < 3; ++ks)
        gh[nf] = mfma16(pack_bf8(relh + j * 96 + ks * 32 + l4 * 8), qf[ks], gh[nf]);
    }
#pragma unroll
    for (int nf = 0; nf < 4; ++nf){
      int j = nf * 16 + l15; if (j > 54) j = 54;
#pragma unroll
      for (int ks = 0; ks < 3; ++ks)
        gw[nf] = mfma16(pack_bf8(relw + j * 96 + ks * 32 + l4 * 8), qf[ks], gw[nf]);
    }
#pragma unroll
    for (int nf = 0; nf < 3; ++nf)
#pragma unroll
      for (int reg = 0; reg < 4; ++reg){
        const int j = h0 + nf * 16 + l4 * 4 + reg;
        const int kh = hh + 27 - j;
        if ((unsigned)kh < 28u) sGh[gbase + kh] = f2bf(gh[nf][reg]);
      }
#pragma unroll
    for (int nf = 0; nf < 4; ++nf)
#pragma unroll
      for (int reg = 0; reg < 4; ++reg){
        const int j = nf * 16 + l4 * 4 + reg;
        const int kw = ww + 27 - j;
        if ((unsigned)kw < 28u) sGw[gbase + kw] = f2bf(gw[nf][reg]);
      }
  }

  float m = -1e30f, lsum = 0.f;
  f32x4 acc[6];
#pragma unroll
  for (int i = 0; i < 6; ++i) acc[i] = z4;

  writeV();
  __syncthreads();   // drains K(0) staging; sV, sG visible

  for (int kt = 0; kt < 13; ++kt){
    const int cur = kt & 1;
    if (kt < 12){ loadV(kt + 1); stageK(kt + 1, cur ^ 1); }

    // ---- S^T = mfma(K, Q): lane holds S^T[k = kt*64+nf*16+l4*4+reg][q = q_l] --
    f32x4 sfr[4] = {z4, z4, z4, z4};
#pragma unroll
    for (int ks = 0; ks < 3; ++ks){
#pragma unroll
      for (int nf = 0; nf < 4; ++nf){
        const int r = nf * 16 + l15;
        const int sl = (ks * 4 + l4) ^ (r & 7);
        const short8 kb = *(const short8*)(sK[cur] + r * 128 + sl * 8);
        sfr[nf] = mfma16(kb, qf[ks], sfr[nf]);
      }
    }

    // ---- logits + lane-local online softmax ----
#pragma unroll
    for (int nf = 0; nf < 4; ++nf){
      const int kb0 = kt * 64 + nf * 16 + l4 * 4;
#pragma unroll
      for (int reg = 0; reg < 4; ++reg){
        const int k = kb0 + reg;
        const int kh = (k * 2341) >> 16;
        const int kw = k - kh * 28;
        float v = sfr[nf][reg] + bf2f(sGh[gbase + kh]) + bf2f(sGw[gbase + kw]);
        if (k >= 784) v = -1e30f;
        sfr[nf][reg] = v;
      }
    }
    float mx;
    {
      float a0 = fmaxf(fmaxf(sfr[0][0], sfr[0][1]), fmaxf(sfr[0][2], sfr[0][3]));
      float a1 = fmaxf(fmaxf(sfr[1][0], sfr[1][1]), fmaxf(sfr[1][2], sfr[1][3]));
      float a2 = fmaxf(fmaxf(sfr[2][0], sfr[2][1]), fmaxf(sfr[2][2], sfr[2][3]));
      float a3 = fmaxf(fmaxf(sfr[3][0], sfr[3][1]), fmaxf(sfr[3][2], sfr[3][3]));
      mx = fmaxf(fmaxf(a0, a1), fmaxf(a2, a3));
    }
    mx = fmaxf(mx, __shfl_xor(mx, 16));
    mx = fmaxf(mx, __shfl_xor(mx, 32));
    const float mn = fmaxf(m, mx);
    const float al = __expf(m - mn);
    m = mn;
    float sum;
    {
#pragma unroll
      for (int nf = 0; nf < 4; ++nf)
#pragma unroll
        for (int reg = 0; reg < 4; ++reg)
          sfr[nf][reg] = __expf(sfr[nf][reg] - mn);
      float s0 = (sfr[0][0] + sfr[0][1]) + (sfr[0][2] + sfr[0][3]);
      float s1 = (sfr[1][0] + sfr[1][1]) + (sfr[1][2] + sfr[1][3]);
      float s2 = (sfr[2][0] + sfr[2][1]) + (sfr[2][2] + sfr[2][3]);
      float s3 = (sfr[3][0] + sfr[3][1]) + (sfr[3][2] + sfr[3][3]);
      sum = (s0 + s1) + (s2 + s3);
    }
    sum += __shfl_xor(sum, 16);
    sum += __shfl_xor(sum, 32);
    lsum = lsum * al + sum;

    // ---- P^T -> sP rows [q][k], 4 x ds_write_b64 (per-wave-private rows) ----
#pragma unroll
    for (int nf = 0; nf < 4; ++nf){
      short4v p4;
      p4[0] = (short)f2bf(sfr[nf][0]); p4[1] = (short)f2bf(sfr[nf][1]);
      p4[2] = (short)f2bf(sfr[nf][2]); p4[3] = (short)f2bf(sfr[nf][3]);
      char* dst = (char*)sP + qrl * 128 + (((nf * 2 + (l4 >> 1)) ^ (l15 & 7)) << 4) + ((l4 & 1) << 3);
      *(short4v*)dst = p4;
    }
    // rescale O^T by per-lane alpha
#pragma unroll
    for (int i = 0; i < 6; ++i)
#pragma unroll
      for (int reg = 0; reg < 4; ++reg)
        acc[i][reg] *= al;

    // ---- O^T += mfma(V^T, P) ----
#pragma unroll
    for (int ks = 0; ks < 2; ++ks){
      const short8 pb = *(const short8*)((char*)sP + qrl * 128 + (((ks * 4 + l4) ^ (l15 & 7)) << 4));
#pragma unroll
      for (int nf = 0; nf < 6; ++nf){
        const int r = nf * 16 + l15;
        const int sl = (ks * 4 + l4) ^ (r & 7);
        const short8 vb = *(const short8*)(sV + r * 64 + sl * 8);
        acc[nf] = mfma16(vb, pb, acc[nf]);
      }
    }

    if (kt < 12){
      __syncthreads();   // B1: all PV reads of sV done; drains staging loads
      writeV();
      __syncthreads();   // B2: sV(t+1) visible to all
    }
  }

  // ---- epilogue: O[q][d] = O^T/lsum + residual ----
  const int qg = qb * 128 + qrl;
  if (qg < 784){
    const float rcp = 1.f / lsum;
    const float* qrow = qpf + base + (size_t)qg * 96;
    float* orow = out + ((size_t)b * 784 + qg) * 384 + h * 96;
#pragma unroll
    for (int nf = 0; nf < 6; ++nf)
#pragma unroll
      for (int reg = 0; reg < 4; ++reg){
        const int d = nf * 16 + l4 * 4 + reg;
        orow[d] = acc[nf][reg] * rcp + qrow[d];
      }
  }
}

// ---------------- launcher -----------------------------------------------------
extern "C" void kernel_launch(void* const* d_in, const int* in_sizes, int n_in,
                              void* d_out, int out_size, void* d_ws, size_t ws_size,
                              hipStream_t stream){
  const float* hs  = (const float*)d_in[0];
  const float* qw  = (const float*)d_in[1];
  const float* qb  = (const float*)d_in[2];
  const float* pwq = (const float*)d_in[3];
  const float* pwk = (const float*)d_in[4];
  const float* pwv = (const float*)d_in[5];
  const float* gq  = (const float*)d_in[6];
  const float* bq  = (const float*)d_in[7];
  const float* gk  = (const float*)d_in[8];
  const float* bk  = (const float*)d_in[9];
  const float* gv  = (const float*)d_in[10];
  const float* bv  = (const float*)d_in[11];
  const float* rh  = (const float*)d_in[12];
  const float* rw  = (const float*)d_in[13];
  float* out = (float*)d_out;

  char* ws = (char*)d_ws;
  size_t off = 0;
  auto take = [&](size_t n)->char*{ char* p = ws + off; off += (n + 255) & ~(size_t)255; return p; };
  unsigned short* hsb = (unsigned short*)take((size_t)50176 * 192 * 2);
  unsigned short* wtb = (unsigned short*)take((size_t)1152 * 192 * 2);
  unsigned short* qkv = (unsigned short*)take((size_t)50176 * 1152 * 2);
  unsigned short* qpb = (unsigned short*)take((size_t)64 * 784 * 96 * 2);
  unsigned short* kpb = (unsigned short*)take((size_t)64 * 784 * 96 * 2);
  unsigned short* vpt = (unsigned short*)take((size_t)64 * 784 * 96 * 2);
  float* qpf          = (float*)take((size_t)64 * 784 * 96 * 4);

  hipLaunchKernelGGL(k_convert, dim3(1024), dim3(256), 0, stream,
                     (const float4*)hs, qw, hsb, wtb);
  hipLaunchKernelGGL(k_gemm, dim3(392 * 9), dim3(256), 0, stream, hsb, wtb, qb, qkv);
  hipLaunchKernelGGL(k_pool_ln, dim3(5376), dim3(256), 0, stream, qkv,
                     pwq, pwk, pwv, gq, bq, gk, bk, gv, bv, qpb, kpb, vpt, qpf);
  hipLaunchKernelGGL(k_attn, dim3(448), dim3(512), 0, stream,
                     qpb, kpb, vpt, qpf, rh, rw, out);
}

// Round 4
// 272.130 us; speedup vs baseline: 1.6717x; 1.1778x over previous
//
#include <hip/hip_runtime.h>

#define DEVI __device__ __forceinline__

typedef __attribute__((ext_vector_type(8))) short short8;
typedef __attribute__((ext_vector_type(4))) short short4v;
typedef __attribute__((ext_vector_type(4))) float f32x4;
typedef __attribute__((ext_vector_type(4))) unsigned int u32x4;

#define ATTN_SCALE 0.10206207261596575f  // 96^-0.5

DEVI unsigned short f2bf(float f){
  unsigned u = __float_as_uint(f);
  u += 0x7fff + ((u >> 16) & 1);          // RNE
  return (unsigned short)(u >> 16);
}
DEVI float bf2f(unsigned short h){ return __uint_as_float(((unsigned)h) << 16); }

DEVI void gload16(const void* g, void* l){
  __builtin_amdgcn_global_load_lds((const __attribute__((address_space(1))) void*)g,
                                   (__attribute__((address_space(3))) void*)l, 16, 0, 0);
}

DEVI f32x4 mfma16(short8 a, short8 b, f32x4 c){
  return __builtin_amdgcn_mfma_f32_16x16x32_bf16(a, b, c, 0, 0, 0);
}

DEVI short8 pack_bf8(const float* p){   // 8 consecutive f32 -> bf16 x8
  float4 a = *(const float4*)p, b = *(const float4*)(p + 4);
  short8 r;
  r[0] = f2bf(a.x); r[1] = f2bf(a.y); r[2] = f2bf(a.z); r[3] = f2bf(a.w);
  r[4] = f2bf(b.x); r[5] = f2bf(b.y); r[6] = f2bf(b.z); r[7] = f2bf(b.w);
  return r;
}

// ---------------- K1: f32 -> bf16 convert (hidden), convert+transpose (qkv_w) ---
__global__ __launch_bounds__(256) void k_convert(const float4* __restrict__ hs4,
    const float* __restrict__ w, unsigned short* __restrict__ hsb,
    unsigned short* __restrict__ wt){
  const int stride = gridDim.x * 256;
  const int t0 = blockIdx.x * 256 + threadIdx.x;
  const int n4 = (50176 * 192) / 4;
  for (int i = t0; i < n4; i += stride){
    float4 v = hs4[i];
    uint2 p;
    p.x = (unsigned)f2bf(v.x) | ((unsigned)f2bf(v.y) << 16);
    p.y = (unsigned)f2bf(v.z) | ((unsigned)f2bf(v.w) << 16);
    ((uint2*)hsb)[i] = p;
  }
  for (int i = t0; i < 192 * 1152; i += stride){
    int k = i / 1152, n = i - k * 1152;
    wt[n * 192 + k] = f2bf(w[i]);
  }
}

// ---------------- K2: QKV GEMM  C[50176,1152] = A[50176,192] * W[192,1152] + b --
__global__ __launch_bounds__(256) void k_gemm(const unsigned short* __restrict__ A,
    const unsigned short* __restrict__ Bt,   // [1152][192] (pre-transposed, K-major)
    const float* __restrict__ bias, unsigned short* __restrict__ C){
  __shared__ unsigned short sA[2][128 * 64];
  __shared__ unsigned short sB[2][128 * 64];
  // bijective XCD swizzle: 3528 = 8 * 441
  const int bid = (blockIdx.x & 7) * 441 + (blockIdx.x >> 3);
  const int bn = bid % 9, bm = bid / 9;
  const int tid = threadIdx.x, w = tid >> 6, l = tid & 63;
  const int wr = (w >> 1) * 64, wc = (w & 1) * 64;
  const int l15 = l & 15, l4 = l >> 4;
  const f32x4 z4 = {0.f, 0.f, 0.f, 0.f};
  f32x4 acc[4][4];
#pragma unroll
  for (int i = 0; i < 4; ++i)
#pragma unroll
    for (int j = 0; j < 4; ++j) acc[i][j] = z4;

  auto stage = [&](int kk, int buf){
    const int k0 = kk * 64;
#pragma unroll
    for (int i = 0; i < 4; ++i){
      const int ib = (w * 4 + i) << 10;
      const int Lb = ib + (l << 4);
      const int r  = Lb >> 7;
      const int g  = ((Lb >> 4) & 7) ^ (r & 7);
      gload16((const char*)A  + (size_t)(bm * 128 + r) * 384 + k0 * 2 + g * 16, (char*)sA[buf] + ib);
      gload16((const char*)Bt + (size_t)(bn * 128 + r) * 384 + k0 * 2 + g * 16, (char*)sB[buf] + ib);
    }
  };

  stage(0, 0);
  __syncthreads();
  for (int kk = 0; kk < 3; ++kk){
    const int buf = kk & 1;
    if (kk < 2) stage(kk + 1, buf ^ 1);
#pragma unroll
    for (int ks = 0; ks < 2; ++ks){
      short8 av[4], bv[4];
#pragma unroll
      for (int mf = 0; mf < 4; ++mf){
        const int r = wr + mf * 16 + l15;
        const int slot = (ks * 4 + l4) ^ (r & 7);
        av[mf] = *(const short8*)(sA[buf] + r * 64 + slot * 8);
      }
#pragma unroll
      for (int nf = 0; nf < 4; ++nf){
        const int r = wc + nf * 16 + l15;
        const int slot = (ks * 4 + l4) ^ (r & 7);
        bv[nf] = *(const short8*)(sB[buf] + r * 64 + slot * 8);
      }
#pragma unroll
      for (int mf = 0; mf < 4; ++mf)
#pragma unroll
        for (int nf = 0; nf < 4; ++nf)
          acc[mf][nf] = mfma16(av[mf], bv[nf], acc[mf][nf]);
    }
    if (kk < 2) __syncthreads();
  }
#pragma unroll
  for (int nf = 0; nf < 4; ++nf){
    const int col = bn * 128 + wc + nf * 16 + l15;
    const float bv = bias[col];
#pragma unroll
    for (int mf = 0; mf < 4; ++mf)
#pragma unroll
      for (int reg = 0; reg < 4; ++reg){
        const int row = bm * 128 + wr + mf * 16 + l4 * 4 + reg;
        C[(size_t)row * 1152 + col] = f2bf(acc[mf][nf][reg] + bv);
      }
  }
}

// ---------------- K3: depthwise 3x3 s2 pool + LayerNorm (vectorized) -----------
// ATTN_SCALE folded into kp (QK^T only); qp unscaled (G tables + QK + residual).
// 384 thr: conv phase 336 items (28 ox x 12 d-octets), short8 loads + bit-unpack;
// LN phase 8 lanes/row (28 rows in one pass).
__global__ __launch_bounds__(384) void k_pool_ln(const unsigned short* __restrict__ qkv,
    const float* __restrict__ wq, const float* __restrict__ wk, const float* __restrict__ wv,
    const float* __restrict__ gq, const float* __restrict__ bq,
    const float* __restrict__ gk, const float* __restrict__ bk,
    const float* __restrict__ gv, const float* __restrict__ bv,
    unsigned short* __restrict__ qp, unsigned short* __restrict__ kp,
    unsigned short* __restrict__ vpt, float* __restrict__ qpf){
  __shared__ float swt[9 * 96];          // weights transposed [tap][d]
  __shared__ float sg[96], sb[96];
  __shared__ float sbuf[28 * 96];
  const int bid = blockIdx.x;
  const int oy = bid % 28, h = (bid / 28) & 3, b = (bid / 112) & 15, which = bid / 1792;
  const float* wsel = which == 0 ? wq : (which == 1 ? wk : wv);
  const float* gsel = which == 0 ? gq : (which == 1 ? gk : gv);
  const float* bsel = which == 0 ? bq : (which == 1 ? bk : bv);
  const int tid = threadIdx.x;
  for (int i = tid; i < 864; i += 384){
    const int d = i / 9, t = i - d * 9;
    swt[t * 96 + d] = wsel[i];
  }
  if (tid < 96){ sg[tid] = gsel[tid]; sb[tid] = bsel[tid]; }
  __syncthreads();

  const int colbase = which * 384 + h * 96;
  if (tid < 336){
    const int ox = tid / 12, d0 = (tid - ox * 12) * 8;
    float acc[8] = {0.f,0.f,0.f,0.f,0.f,0.f,0.f,0.f};
#pragma unroll
    for (int ky = 0; ky < 3; ++ky){
      const int iy = oy * 2 + ky - 1;
      if ((unsigned)iy >= 56u) continue;
      const unsigned short* rowp = qkv + (size_t)(b * 3136 + iy * 56) * 1152 + colbase + d0;
#pragma unroll
      for (int kx = 0; kx < 3; ++kx){
        const int ix = ox * 2 + kx - 1;
        if ((unsigned)ix >= 56u) continue;
        const u32x4 raw = *(const u32x4*)(rowp + (size_t)ix * 1152);
        const float* wv8 = swt + (ky * 3 + kx) * 96 + d0;
        const float4 wa = *(const float4*)wv8;
        const float4 wb = *(const float4*)(wv8 + 4);
        acc[0] += __uint_as_float(raw[0] << 16)         * wa.x;
        acc[1] += __uint_as_float(raw[0] & 0xffff0000u) * wa.y;
        acc[2] += __uint_as_float(raw[1] << 16)         * wa.z;
        acc[3] += __uint_as_float(raw[1] & 0xffff0000u) * wa.w;
        acc[4] += __uint_as_float(raw[2] << 16)         * wb.x;
        acc[5] += __uint_as_float(raw[2] & 0xffff0000u) * wb.y;
        acc[6] += __uint_as_float(raw[3] << 16)         * wb.z;
        acc[7] += __uint_as_float(raw[3] & 0xffff0000u) * wb.w;
      }
    }
    *(float4*)(sbuf + ox * 96 + d0)     = *(float4*)acc;
    *(float4*)(sbuf + ox * 96 + d0 + 4) = *(float4*)(acc + 4);
  }
  __syncthreads();

  // LN: 8 lanes per row, 12 channels per lane, 28 rows in one pass
  const int grp = tid >> 3, l8 = tid & 7;
  if (grp < 28){
    const int ox = grp, d0 = l8 * 12;
    float x[12];
    *(float4*)x       = *(const float4*)(sbuf + ox * 96 + d0);
    *(float4*)(x + 4) = *(const float4*)(sbuf + ox * 96 + d0 + 4);
    *(float4*)(x + 8) = *(const float4*)(sbuf + ox * 96 + d0 + 8);
    float s = 0.f, ss = 0.f;
#pragma unroll
    for (int j = 0; j < 12; ++j){ s += x[j]; ss += x[j] * x[j]; }
#pragma unroll
    for (int d = 1; d < 8; d <<= 1){ s += __shfl_xor(s, d); ss += __shfl_xor(ss, d); }
    const float mean = s * (1.f / 96.f);
    const float var  = ss * (1.f / 96.f) - mean * mean;
    const float rstd = rsqrtf(var + 1e-6f);
    const int n = oy * 28 + ox;
    const size_t bh = (size_t)(b * 4 + h);
    float y[12];
#pragma unroll
    for (int j = 0; j < 12; ++j)
      y[j] = (x[j] - mean) * rstd * sg[d0 + j] + sb[d0 + j];
    if (which == 0){
      const size_t idx = (bh * 784 + n) * 96 + d0;
#pragma unroll
      for (int c = 0; c < 3; ++c){
        short4v p;
        p[0] = (short)f2bf(y[c*4]);   p[1] = (short)f2bf(y[c*4+1]);
        p[2] = (short)f2bf(y[c*4+2]); p[3] = (short)f2bf(y[c*4+3]);
        *(short4v*)(qp + idx + c * 4) = p;
        *(float4*)(qpf + idx + c * 4) = *(const float4*)(y + c * 4);
      }
    } else if (which == 1){
      const size_t idx = (bh * 784 + n) * 96 + d0;
#pragma unroll
      for (int c = 0; c < 3; ++c){
        short4v p;
        p[0] = (short)f2bf(y[c*4]   * ATTN_SCALE); p[1] = (short)f2bf(y[c*4+1] * ATTN_SCALE);
        p[2] = (short)f2bf(y[c*4+2] * ATTN_SCALE); p[3] = (short)f2bf(y[c*4+3] * ATTN_SCALE);
        *(short4v*)(kp + idx + c * 4) = p;
      }
    } else {
#pragma unroll
      for (int j = 0; j < 12; ++j)
        vpt[(bh * 96 + d0 + j) * 784 + n] = f2bf(y[j]);
    }
  }
}

// ---------------- K4: fused attention, swapped-operand flash ------------------
// 512 thr, 128 q-rows/block. S^T = mfma(K,Q): softmax is lane-local + 2 shfl.
// Rel-pos tables G computed by MFMA. K dbuf gload_lds; V reg-staged (T14).
__global__ __launch_bounds__(512, 4) void k_attn(
    const unsigned short* __restrict__ qp, const unsigned short* __restrict__ kp,
    const unsigned short* __restrict__ vpt, const float* __restrict__ qpf,
    const float* __restrict__ relh, const float* __restrict__ relw,
    float* __restrict__ out){
  __shared__ unsigned short sK[2][64 * 128];   // 32KB (256B rows, swizzled granules)
  __shared__ unsigned short sV[96 * 64];       // 12KB V^T tile [d][k]
  __shared__ unsigned short sP[128 * 64];      // 16KB P^T-as-[q][k], swizzled
  __shared__ unsigned short sGh[128 * 34];     // 8.5KB, [q_local][kh]
  __shared__ unsigned short sGw[128 * 34];     // 8.5KB, [q_local][kw]

  // XCD mapping: all 7 q-blocks of one bh land on one XCD (K/V L2-resident)
  const int s = blockIdx.x, xcd = s & 7, slot = s >> 3;
  const int bh = xcd * 8 + slot / 7, qb = slot - (slot / 7) * 7;
  const int b = bh >> 2, h = bh & 3;
  const int tid = threadIdx.x, w = tid >> 6, l = tid & 63;
  const int l15 = l & 15, l4 = l >> 4;
  const size_t base = (size_t)bh * 784 * 96;
  const f32x4 z4 = {0.f, 0.f, 0.f, 0.f};
  const int qrl = w * 16 + l15;                 // local q row 0..127
  int q_l = qb * 128 + qrl; if (q_l > 783) q_l = 783;
  const int gbase = qrl * 34;

  auto stageK = [&](int t, int buf){
#pragma unroll
    for (int i = 0; i < 2; ++i){
      const int ib = (w * 2 + i) << 10;
      const int Lb = ib + (l << 4);
      const int r = Lb >> 8;                     // 256B rows
      const int g = ((Lb >> 4) & 15) ^ (r & 7);
      int kr = t * 64 + r; if (kr > 783) kr = 783;
      const size_t gb = (base + (size_t)kr * 96) * 2 + (g < 12 ? g * 16 : 0);
      gload16((const char*)kp + gb, (char*)sK[buf] + ib);
    }
  };
  short8 vreg[2];
  auto loadV = [&](int t){
    if (tid < 384){
#pragma unroll
      for (int i = 0; i < 2; ++i){
        const int off = (tid * 2 + i) << 4;      // bytes in sV
        const int r = off >> 7;                  // d row (128B rows)
        const int g = ((off >> 4) & 7) ^ (r & 7);
        int koff = t * 64 + g * 8; if (koff + 8 > 784) koff = 0;  // masked by P=0
        vreg[i] = *(const short8*)(vpt + (size_t)(bh * 96 + r) * 784 + koff);
      }
    }
  };
  auto writeV = [&](){
    if (tid < 384){
#pragma unroll
      for (int i = 0; i < 2; ++i)
        *(short8*)((char*)sV + ((tid * 2 + i) << 4)) = vreg[i];
    }
  };

  stageK(0, 0);
  loadV(0);

  // Q fragments (B-operand layout): lane holds Q[q_l][d = ks*32 + l4*8 + j]
  short8 qf[3];
#pragma unroll
  for (int ks = 0; ks < 3; ++ks)
    qf[ks] = *(const short8*)(qp + base + (size_t)q_l * 96 + ks * 32 + l4 * 8);

  const int hh = (q_l * 2341) >> 16;             // /28 (exact for <=847)
  const int ww = q_l - hh * 28;
  const int h0 = (qb * 128) / 28;

  // G tables via MFMA: G[j][q] = dot(rel[j], q). Gh window j in [h0,h0+47].
  {
    f32x4 gh[3] = {z4, z4, z4}, gw[4] = {z4, z4, z4, z4};
#pragma unroll
    for (int nf = 0; nf < 3; ++nf){
      int j = h0 + nf * 16 + l15; if (j > 54) j = 54;
#pragma unroll
      for (int ks = 0; ks < 3; ++ks)
        gh[nf] = mfma16(pack_bf8(relh + j * 96 + ks * 32 + l4 * 8), qf[ks], gh[nf]);
    }
#pragma unroll
    for (int nf = 0; nf < 4; ++nf){
      int j = nf * 16 + l15; if (j > 54) j = 54;
#pragma unroll
      for (int ks = 0; ks < 3; ++ks)
        gw[nf] = mfma16(pack_bf8(relw + j * 96 + ks * 32 + l4 * 8), qf[ks], gw[nf]);
    }
#pragma unroll
    for (int nf = 0; nf < 3; ++nf)
#pragma unroll
      for (int reg = 0; reg < 4; ++reg){
        const int j = h0 + nf * 16 + l4 * 4 + reg;
        const int kh = hh + 27 - j;
        if ((unsigned)kh < 28u) sGh[gbase + kh] = f2bf(gh[nf][reg]);
      }
#pragma unroll
    for (int nf = 0; nf < 4; ++nf)
#pragma unroll
      for (int reg = 0; reg < 4; ++reg){
        const int j = nf * 16 + l4 * 4 + reg;
        const int kw = ww + 27 - j;
        if ((unsigned)kw < 28u) sGw[gbase + kw] = f2bf(gw[nf][reg]);
      }
  }

  float m = -1e30f, lsum = 0.f;
  f32x4 acc[6];
#pragma unroll
  for (int i = 0; i < 6; ++i) acc[i] = z4;

  writeV();
  __syncthreads();   // drains K(0) staging; sV, sG visible

  for (int kt = 0; kt < 13; ++kt){
    const int cur = kt & 1;
    if (kt < 12){ loadV(kt + 1); stageK(kt + 1, cur ^ 1); }

    // ---- S^T = mfma(K, Q): lane holds S^T[k = kt*64+nf*16+l4*4+reg][q = q_l] --
    f32x4 sfr[4] = {z4, z4, z4, z4};
#pragma unroll
    for (int ks = 0; ks < 3; ++ks){
#pragma unroll
      for (int nf = 0; nf < 4; ++nf){
        const int r = nf * 16 + l15;
        const int sl = (ks * 4 + l4) ^ (r & 7);
        const short8 kb = *(const short8*)(sK[cur] + r * 128 + sl * 8);
        sfr[nf] = mfma16(kb, qf[ks], sfr[nf]);
      }
    }

    // ---- logits + lane-local online softmax ----
#pragma unroll
    for (int nf = 0; nf < 4; ++nf){
      const int kb0 = kt * 64 + nf * 16 + l4 * 4;
#pragma unroll
      for (int reg = 0; reg < 4; ++reg){
        const int k = kb0 + reg;
        const int kh = (k * 2341) >> 16;
        const int kw = k - kh * 28;
        float v = sfr[nf][reg] + bf2f(sGh[gbase + kh]) + bf2f(sGw[gbase + kw]);
        if (k >= 784) v = -1e30f;
        sfr[nf][reg] = v;
      }
    }
    float mx;
    {
      float a0 = fmaxf(fmaxf(sfr[0][0], sfr[0][1]), fmaxf(sfr[0][2], sfr[0][3]));
      float a1 = fmaxf(fmaxf(sfr[1][0], sfr[1][1]), fmaxf(sfr[1][2], sfr[1][3]));
      float a2 = fmaxf(fmaxf(sfr[2][0], sfr[2][1]), fmaxf(sfr[2][2], sfr[2][3]));
      float a3 = fmaxf(fmaxf(sfr[3][0], sfr[3][1]), fmaxf(sfr[3][2], sfr[3][3]));
      mx = fmaxf(fmaxf(a0, a1), fmaxf(a2, a3));
    }
    mx = fmaxf(mx, __shfl_xor(mx, 16));
    mx = fmaxf(mx, __shfl_xor(mx, 32));
    const float mn = fmaxf(m, mx);
    const float al = __expf(m - mn);
    m = mn;
    float sum;
    {
#pragma unroll
      for (int nf = 0; nf < 4; ++nf)
#pragma unroll
        for (int reg = 0; reg < 4; ++reg)
          sfr[nf][reg] = __expf(sfr[nf][reg] - mn);
      float s0 = (sfr[0][0] + sfr[0][1]) + (sfr[0][2] + sfr[0][3]);
      float s1 = (sfr[1][0] + sfr[1][1]) + (sfr[1][2] + sfr[1][3]);
      float s2 = (sfr[2][0] + sfr[2][1]) + (sfr[2][2] + sfr[2][3]);
      float s3 = (sfr[3][0] + sfr[3][1]) + (sfr[3][2] + sfr[3][3]);
      sum = (s0 + s1) + (s2 + s3);
    }
    sum += __shfl_xor(sum, 16);
    sum += __shfl_xor(sum, 32);
    lsum = lsum * al + sum;

    // ---- P^T -> sP rows [q][k], 4 x ds_write_b64 (per-wave-private rows) ----
#pragma unroll
    for (int nf = 0; nf < 4; ++nf){
      short4v p4;
      p4[0] = (short)f2bf(sfr[nf][0]); p4[1] = (short)f2bf(sfr[nf][1]);
      p4[2] = (short)f2bf(sfr[nf][2]); p4[3] = (short)f2bf(sfr[nf][3]);
      char* dst = (char*)sP + qrl * 128 + (((nf * 2 + (l4 >> 1)) ^ (l15 & 7)) << 4) + ((l4 & 1) << 3);
      *(short4v*)dst = p4;
    }
    // rescale O^T by per-lane alpha
#pragma unroll
    for (int i = 0; i < 6; ++i)
#pragma unroll
      for (int reg = 0; reg < 4; ++reg)
        acc[i][reg] *= al;

    // ---- O^T += mfma(V^T, P) ----
#pragma unroll
    for (int ks = 0; ks < 2; ++ks){
      const short8 pb = *(const short8*)((char*)sP + qrl * 128 + (((ks * 4 + l4) ^ (l15 & 7)) << 4));
#pragma unroll
      for (int nf = 0; nf < 6; ++nf){
        const int r = nf * 16 + l15;
        const int sl = (ks * 4 + l4) ^ (r & 7);
        const short8 vb = *(const short8*)(sV + r * 64 + sl * 8);
        acc[nf] = mfma16(vb, pb, acc[nf]);
      }
    }

    if (kt < 12){
      __syncthreads();   // B1: all PV reads of sV done; drains staging loads
      writeV();
      __syncthreads();   // B2: sV(t+1) visible to all
    }
  }

  // ---- epilogue: O[q][d] = O^T/lsum + residual ----
  const int qg = qb * 128 + qrl;
  if (qg < 784){
    const float rcp = 1.f / lsum;
    const float* qrow = qpf + base + (size_t)qg * 96;
    float* orow = out + ((size_t)b * 784 + qg) * 384 + h * 96;
#pragma unroll
    for (int nf = 0; nf < 6; ++nf)
#pragma unroll
      for (int reg = 0; reg < 4; ++reg){
        const int d = nf * 16 + l4 * 4 + reg;
        orow[d] = acc[nf][reg] * rcp + qrow[d];
      }
  }
}

// ---------------- launcher -----------------------------------------------------
extern "C" void kernel_launch(void* const* d_in, const int* in_sizes, int n_in,
                              void* d_out, int out_size, void* d_ws, size_t ws_size,
                              hipStream_t stream){
  const float* hs  = (const float*)d_in[0];
  const float* qw  = (const float*)d_in[1];
  const float* qb  = (const float*)d_in[2];
  const float* pwq = (const float*)d_in[3];
  const float* pwk = (const float*)d_in[4];
  const float* pwv = (const float*)d_in[5];
  const float* gq  = (const float*)d_in[6];
  const float* bq  = (const float*)d_in[7];
  const float* gk  = (const float*)d_in[8];
  const float* bk  = (const float*)d_in[9];
  const float* gv  = (const float*)d_in[10];
  const float* bv  = (const float*)d_in[11];
  const float* rh  = (const float*)d_in[12];
  const float* rw  = (const float*)d_in[13];
  float* out = (float*)d_out;

  char* ws = (char*)d_ws;
  size_t off = 0;
  auto take = [&](size_t n)->char*{ char* p = ws + off; off += (n + 255) & ~(size_t)255; return p; };
  unsigned short* hsb = (unsigned short*)take((size_t)50176 * 192 * 2);
  unsigned short* wtb = (unsigned short*)take((size_t)1152 * 192 * 2);
  unsigned short* qkv = (unsigned short*)take((size_t)50176 * 1152 * 2);
  unsigned short* qpb = (unsigned short*)take((size_t)64 * 784 * 96 * 2);
  unsigned short* kpb = (unsigned short*)take((size_t)64 * 784 * 96 * 2);
  unsigned short* vpt = (unsigned short*)take((size_t)64 * 784 * 96 * 2);
  float* qpf          = (float*)take((size_t)64 * 784 * 96 * 4);

  hipLaunchKernelGGL(k_convert, dim3(1024), dim3(256), 0, stream,
                     (const float4*)hs, qw, hsb, wtb);
  hipLaunchKernelGGL(k_gemm, dim3(392 * 9), dim3(256), 0, stream, hsb, wtb, qb, qkv);
  hipLaunchKernelGGL(k_pool_ln, dim3(5376), dim3(384), 0, stream, qkv,
                     pwq, pwk, pwv, gq, bq, gk, bk, gv, bv, qpb, kpb, vpt, qpf);
  hipLaunchKernelGGL(k_attn, dim3(448), dim3(512), 0, stream,
                     qpb, kpb, vpt, qpf, rh, rw, out);
}

// Round 5
// 269.836 us; speedup vs baseline: 1.6859x; 1.0085x over previous
//
#include <hip/hip_runtime.h>

#define DEVI __device__ __forceinline__

typedef __attribute__((ext_vector_type(8))) short short8;
typedef __attribute__((ext_vector_type(4))) short short4v;
typedef __attribute__((ext_vector_type(4))) float f32x4;
typedef __attribute__((ext_vector_type(4))) unsigned int u32x4;

#define ATTN_SCALE 0.10206207261596575f  // 96^-0.5
#define LOG2E      1.4426950408889634f
#define KSCALE     (ATTN_SCALE * LOG2E)

DEVI unsigned short f2bf(float f){
  unsigned u = __float_as_uint(f);
  u += 0x7fff + ((u >> 16) & 1);          // RNE
  return (unsigned short)(u >> 16);
}
DEVI float bf2f(unsigned short h){ return __uint_as_float(((unsigned)h) << 16); }

DEVI void gload16(const void* g, void* l){
  __builtin_amdgcn_global_load_lds((const __attribute__((address_space(1))) void*)g,
                                   (__attribute__((address_space(3))) void*)l, 16, 0, 0);
}

DEVI f32x4 mfma16(short8 a, short8 b, f32x4 c){
  return __builtin_amdgcn_mfma_f32_16x16x32_bf16(a, b, c, 0, 0, 0);
}

DEVI short8 pack_bf8s(const float* p, float s){   // 8 f32 * s -> bf16 x8
  float4 a = *(const float4*)p, b = *(const float4*)(p + 4);
  short8 r;
  r[0] = f2bf(a.x * s); r[1] = f2bf(a.y * s); r[2] = f2bf(a.z * s); r[3] = f2bf(a.w * s);
  r[4] = f2bf(b.x * s); r[5] = f2bf(b.y * s); r[6] = f2bf(b.z * s); r[7] = f2bf(b.w * s);
  return r;
}

// ---------------- K1: f32 -> bf16 convert (hidden), convert+transpose (qkv_w) ---
__global__ __launch_bounds__(256) void k_convert(const float4* __restrict__ hs4,
    const float* __restrict__ w, unsigned short* __restrict__ hsb,
    unsigned short* __restrict__ wt){
  const int stride = gridDim.x * 256;
  const int t0 = blockIdx.x * 256 + threadIdx.x;
  const int n4 = (50176 * 192) / 4;
  for (int i = t0; i < n4; i += stride){
    float4 v = hs4[i];
    uint2 p;
    p.x = (unsigned)f2bf(v.x) | ((unsigned)f2bf(v.y) << 16);
    p.y = (unsigned)f2bf(v.z) | ((unsigned)f2bf(v.w) << 16);
    ((uint2*)hsb)[i] = p;
  }
  for (int i = t0; i < 192 * 1152; i += stride){
    int k = i / 1152, n = i - k * 1152;
    wt[n * 192 + k] = f2bf(w[i]);
  }
}

// ---------------- K2: QKV GEMM  C[50176,1152] = A[50176,192] * W[192,1152] + b --
__global__ __launch_bounds__(256) void k_gemm(const unsigned short* __restrict__ A,
    const unsigned short* __restrict__ Bt,   // [1152][192] (pre-transposed, K-major)
    const float* __restrict__ bias, unsigned short* __restrict__ C){
  __shared__ unsigned short sA[2][128 * 64];
  __shared__ unsigned short sB[2][128 * 64];
  // bijective XCD swizzle: 3528 = 8 * 441
  const int bid = (blockIdx.x & 7) * 441 + (blockIdx.x >> 3);
  const int bn = bid % 9, bm = bid / 9;
  const int tid = threadIdx.x, w = tid >> 6, l = tid & 63;
  const int wr = (w >> 1) * 64, wc = (w & 1) * 64;
  const int l15 = l & 15, l4 = l >> 4;
  const f32x4 z4 = {0.f, 0.f, 0.f, 0.f};
  f32x4 acc[4][4];
#pragma unroll
  for (int i = 0; i < 4; ++i)
#pragma unroll
    for (int j = 0; j < 4; ++j) acc[i][j] = z4;

  auto stage = [&](int kk, int buf){
    const int k0 = kk * 64;
#pragma unroll
    for (int i = 0; i < 4; ++i){
      const int ib = (w * 4 + i) << 10;
      const int Lb = ib + (l << 4);
      const int r  = Lb >> 7;
      const int g  = ((Lb >> 4) & 7) ^ (r & 7);
      gload16((const char*)A  + (size_t)(bm * 128 + r) * 384 + k0 * 2 + g * 16, (char*)sA[buf] + ib);
      gload16((const char*)Bt + (size_t)(bn * 128 + r) * 384 + k0 * 2 + g * 16, (char*)sB[buf] + ib);
    }
  };

  stage(0, 0);
  __syncthreads();
  for (int kk = 0; kk < 3; ++kk){
    const int buf = kk & 1;
    if (kk < 2) stage(kk + 1, buf ^ 1);
#pragma unroll
    for (int ks = 0; ks < 2; ++ks){
      short8 av[4], bv[4];
#pragma unroll
      for (int mf = 0; mf < 4; ++mf){
        const int r = wr + mf * 16 + l15;
        const int slot = (ks * 4 + l4) ^ (r & 7);
        av[mf] = *(const short8*)(sA[buf] + r * 64 + slot * 8);
      }
#pragma unroll
      for (int nf = 0; nf < 4; ++nf){
        const int r = wc + nf * 16 + l15;
        const int slot = (ks * 4 + l4) ^ (r & 7);
        bv[nf] = *(const short8*)(sB[buf] + r * 64 + slot * 8);
      }
#pragma unroll
      for (int mf = 0; mf < 4; ++mf)
#pragma unroll
        for (int nf = 0; nf < 4; ++nf)
          acc[mf][nf] = mfma16(av[mf], bv[nf], acc[mf][nf]);
    }
    if (kk < 2) __syncthreads();
  }
#pragma unroll
  for (int nf = 0; nf < 4; ++nf){
    const int col = bn * 128 + wc + nf * 16 + l15;
    const float bv = bias[col];
#pragma unroll
    for (int mf = 0; mf < 4; ++mf)
#pragma unroll
      for (int reg = 0; reg < 4; ++reg){
        const int row = bm * 128 + wr + mf * 16 + l4 * 4 + reg;
        C[(size_t)row * 1152 + col] = f2bf(acc[mf][nf][reg] + bv);
      }
  }
}

// ---------------- K3: depthwise 3x3 s2 pool + LayerNorm (vectorized) -----------
// kp is the EXTENDED K' [bh][784][160]: cols 0-95 = K*KSCALE (bf16),
// 96-123 = onehot(kh=n/28), 124-127 = 0, 128-155 = onehot(kw=n%28), 156-159 = 0.
__global__ __launch_bounds__(384) void k_pool_ln(const unsigned short* __restrict__ qkv,
    const float* __restrict__ wq, const float* __restrict__ wk, const float* __restrict__ wv,
    const float* __restrict__ gq, const float* __restrict__ bq,
    const float* __restrict__ gk, const float* __restrict__ bk,
    const float* __restrict__ gv, const float* __restrict__ bv,
    unsigned short* __restrict__ qp, unsigned short* __restrict__ kp,
    unsigned short* __restrict__ vpt, float* __restrict__ qpf){
  __shared__ float swt[9 * 96];          // weights transposed [tap][d]
  __shared__ float sg[96], sb[96];
  __shared__ float sbuf[28 * 96];
  const int bid = blockIdx.x;
  const int oy = bid % 28, h = (bid / 28) & 3, b = (bid / 112) & 15, which = bid / 1792;
  const float* wsel = which == 0 ? wq : (which == 1 ? wk : wv);
  const float* gsel = which == 0 ? gq : (which == 1 ? gk : gv);
  const float* bsel = which == 0 ? bq : (which == 1 ? bk : bv);
  const int tid = threadIdx.x;
  for (int i = tid; i < 864; i += 384){
    const int d = i / 9, t = i - d * 9;
    swt[t * 96 + d] = wsel[i];
  }
  if (tid < 96){ sg[tid] = gsel[tid]; sb[tid] = bsel[tid]; }
  __syncthreads();

  const int colbase = which * 384 + h * 96;
  if (tid < 336){
    const int ox = tid / 12, d0 = (tid - ox * 12) * 8;
    float acc[8] = {0.f,0.f,0.f,0.f,0.f,0.f,0.f,0.f};
#pragma unroll
    for (int ky = 0; ky < 3; ++ky){
      const int iy = oy * 2 + ky - 1;
      if ((unsigned)iy >= 56u) continue;
      const unsigned short* rowp = qkv + (size_t)(b * 3136 + iy * 56) * 1152 + colbase + d0;
#pragma unroll
      for (int kx = 0; kx < 3; ++kx){
        const int ix = ox * 2 + kx - 1;
        if ((unsigned)ix >= 56u) continue;
        const u32x4 raw = *(const u32x4*)(rowp + (size_t)ix * 1152);
        const float* wv8 = swt + (ky * 3 + kx) * 96 + d0;
        const float4 wa = *(const float4*)wv8;
        const float4 wb = *(const float4*)(wv8 + 4);
        acc[0] += __uint_as_float(raw[0] << 16)         * wa.x;
        acc[1] += __uint_as_float(raw[0] & 0xffff0000u) * wa.y;
        acc[2] += __uint_as_float(raw[1] << 16)         * wa.z;
        acc[3] += __uint_as_float(raw[1] & 0xffff0000u) * wa.w;
        acc[4] += __uint_as_float(raw[2] << 16)         * wb.x;
        acc[5] += __uint_as_float(raw[2] & 0xffff0000u) * wb.y;
        acc[6] += __uint_as_float(raw[3] << 16)         * wb.z;
        acc[7] += __uint_as_float(raw[3] & 0xffff0000u) * wb.w;
      }
    }
    *(float4*)(sbuf + ox * 96 + d0)     = *(float4*)acc;
    *(float4*)(sbuf + ox * 96 + d0 + 4) = *(float4*)(acc + 4);
  }
  __syncthreads();

  // LN: 8 lanes per row, 12 channels per lane, 28 rows in one pass
  const int grp = tid >> 3, l8 = tid & 7;
  if (grp < 28){
    const int ox = grp, d0 = l8 * 12;
    float x[12];
    *(float4*)x       = *(const float4*)(sbuf + ox * 96 + d0);
    *(float4*)(x + 4) = *(const float4*)(sbuf + ox * 96 + d0 + 4);
    *(float4*)(x + 8) = *(const float4*)(sbuf + ox * 96 + d0 + 8);
    float s = 0.f, ss = 0.f;
#pragma unroll
    for (int j = 0; j < 12; ++j){ s += x[j]; ss += x[j] * x[j]; }
#pragma unroll
    for (int d = 1; d < 8; d <<= 1){ s += __shfl_xor(s, d); ss += __shfl_xor(ss, d); }
    const float mean = s * (1.f / 96.f);
    const float var  = ss * (1.f / 96.f) - mean * mean;
    const float rstd = rsqrtf(var + 1e-6f);
    const int n = oy * 28 + ox;
    const size_t bh = (size_t)(b * 4 + h);
    float y[12];
#pragma unroll
    for (int j = 0; j < 12; ++j)
      y[j] = (x[j] - mean) * rstd * sg[d0 + j] + sb[d0 + j];
    if (which == 0){
      const size_t idx = (bh * 784 + n) * 96 + d0;
#pragma unroll
      for (int c = 0; c < 3; ++c){
        short4v p;
        p[0] = (short)f2bf(y[c*4]);   p[1] = (short)f2bf(y[c*4+1]);
        p[2] = (short)f2bf(y[c*4+2]); p[3] = (short)f2bf(y[c*4+3]);
        *(short4v*)(qp + idx + c * 4) = p;
        *(float4*)(qpf + idx + c * 4) = *(const float4*)(y + c * 4);
      }
    } else if (which == 1){
      const size_t idx = (bh * 784 + n) * 160;
#pragma unroll
      for (int c = 0; c < 3; ++c){
        short4v p;
        p[0] = (short)f2bf(y[c*4]   * KSCALE); p[1] = (short)f2bf(y[c*4+1] * KSCALE);
        p[2] = (short)f2bf(y[c*4+2] * KSCALE); p[3] = (short)f2bf(y[c*4+3] * KSCALE);
        *(short4v*)(kp + idx + d0 + c * 4) = p;
      }
      // one-hot extension granule (8 shorts at col 96 + l8*8)
      short8 oh;
#pragma unroll
      for (int jj = 0; jj < 8; ++jj){
        const int pcol = 96 + l8 * 8 + jj;
        unsigned short v = 0;
        if (pcol == 96 + oy)  v = 0x3F80;   // 1.0 bf16
        if (pcol == 128 + ox) v = 0x3F80;
        oh[jj] = (short)v;
      }
      *(short8*)(kp + idx + 96 + l8 * 8) = oh;
    } else {
#pragma unroll
      for (int j = 0; j < 12; ++j)
        vpt[(bh * 96 + d0 + j) * 784 + n] = f2bf(y[j]);
    }
  }
}

// ---------------- K4: fused attention, one-hot rel-pos in the MFMA ------------
// 512 thr, 128 q-rows. S'^T = mfma(K', Q') emits finished log2-domain logits
// (K' = [K*scale*log2e | onehot_kh | onehot_kw], Q' = [Q | Gh | Gw]).
// sP overlays sK[cur]; G tables overlay sK[1] pre-loop. LDS = 52KB.
__global__ __launch_bounds__(512, 4) void k_attn(
    const unsigned short* __restrict__ qp, const unsigned short* __restrict__ kp,
    const unsigned short* __restrict__ vpt, const float* __restrict__ qpf,
    const float* __restrict__ relh, const float* __restrict__ relw,
    float* __restrict__ out){
  __shared__ unsigned short sK[2][64 * 160];   // 2 x 20KB (320B rows, granule^ (r&3))
  __shared__ unsigned short sV[96 * 64];       // 12KB V^T tile [d][k]

  // XCD mapping: all 7 q-blocks of one bh land on one XCD (K/V L2-resident)
  const int s = blockIdx.x, xcd = s & 7, slot = s >> 3;
  const int bh = xcd * 8 + slot / 7, qb = slot - (slot / 7) * 7;
  const int b = bh >> 2, h = bh & 3;
  const int tid = threadIdx.x, w = tid >> 6, l = tid & 63;
  const int l15 = l & 15, l4 = l >> 4;
  const size_t baseq = (size_t)bh * 784 * 96;
  const size_t basek = (size_t)bh * 784 * 160;
  const f32x4 z4 = {0.f, 0.f, 0.f, 0.f};
  const int qrl = w * 16 + l15;                 // local q row 0..127
  int q_l = qb * 128 + qrl; if (q_l > 783) q_l = 783;

  // ---- K' staging: 20KB/tile, wave-linear LDS dest, pre-swizzled source ----
  auto stageK = [&](int t, int buf){
#pragma unroll
    for (int r = 0; r < 3; ++r){
      if (r == 2 && tid >= 256) continue;        // wave-uniform guard
      const int off = r * 8192 + (tid << 4);     // bytes into sK[buf]
      const int row = ((off >> 6) * 205) >> 10;  // off / 320
      const int rem = off - row * 320;
      const int sg_ = (rem >> 4) ^ (row & 3);    // source granule (involution)
      int kr = t * 64 + row; if (kr > 783) kr = 783;
      gload16((const char*)kp + ((size_t)(basek + (size_t)kr * 160) + sg_ * 8) * 2,
              (char*)sK[buf] + off);
    }
  };
  short8 vreg[2];
  auto loadV = [&](int t){
    if (tid < 384){
#pragma unroll
      for (int i = 0; i < 2; ++i){
        const int off = (tid * 2 + i) << 4;      // bytes in sV
        const int r = off >> 7;                  // d row (128B rows)
        const int g = ((off >> 4) & 7) ^ (r & 7);
        int koff = t * 64 + g * 8; if (koff + 8 > 784) koff = 0;  // masked by P=0
        vreg[i] = *(const short8*)(vpt + (size_t)(bh * 96 + r) * 784 + koff);
      }
    }
  };
  auto writeV = [&](){
    if (tid < 384){
#pragma unroll
      for (int i = 0; i < 2; ++i)
        *(short8*)((char*)sV + ((tid * 2 + i) << 4)) = vreg[i];
    }
  };

  stageK(0, 0);
  loadV(0);

  // ---- Q' fragments: qf[0..2] = Q (bf16), qf[3] = Gh, qf[4] = Gw ----
  short8 qf[5];
#pragma unroll
  for (int ks = 0; ks < 3; ++ks)
    qf[ks] = *(const short8*)(qp + baseq + (size_t)q_l * 96 + ks * 32 + l4 * 8);

  const int hh = (q_l * 2341) >> 16;             // /28 (exact for <=847)
  const int ww = q_l - hh * 28;
  const int h0 = (qb * 128) / 28;

  // G tables via MFMA (log2e folded into rel): G[j][q] = dot(rel[j]*log2e, q)
  {
    unsigned short* sGh = sK[1];                 // overlay (freed before kt=0 staging)
    unsigned short* sGw = sK[1] + 4096;          // +8KB
    f32x4 gh[3] = {z4, z4, z4}, gw[4] = {z4, z4, z4, z4};
#pragma unroll
    for (int nf = 0; nf < 3; ++nf){
      int j = h0 + nf * 16 + l15; if (j > 54) j = 54;
#pragma unroll
      for (int ks = 0; ks < 3; ++ks)
        gh[nf] = mfma16(pack_bf8s(relh + j * 96 + ks * 32 + l4 * 8, LOG2E), qf[ks], gh[nf]);
    }
#pragma unroll
    for (int nf = 0; nf < 4; ++nf){
      int j = nf * 16 + l15; if (j > 54) j = 54;
#pragma unroll
      for (int ks = 0; ks < 3; ++ks)
        gw[nf] = mfma16(pack_bf8s(relw + j * 96 + ks * 32 + l4 * 8, LOG2E), qf[ks], gw[nf]);
    }
    // scatter into [q][32]-padded rows; zero the 4 pad cols (NaN safety)
    if (l4 == 0){
      *(short4v*)(sGh + qrl * 32 + 28) = (short4v)0;
      *(short4v*)(sGw + qrl * 32 + 28) = (short4v)0;
    }
#pragma unroll
    for (int nf = 0; nf < 3; ++nf)
#pragma unroll
      for (int reg = 0; reg < 4; ++reg){
        const int j = h0 + nf * 16 + l4 * 4 + reg;
        const int kh = hh + 27 - j;
        if ((unsigned)kh < 28u) sGh[qrl * 32 + kh] = f2bf(gh[nf][reg]);
      }
#pragma unroll
    for (int nf = 0; nf < 4; ++nf)
#pragma unroll
      for (int reg = 0; reg < 4; ++reg){
        const int j = nf * 16 + l4 * 4 + reg;
        const int kw = ww + 27 - j;
        if ((unsigned)kw < 28u) sGw[qrl * 32 + kw] = f2bf(gw[nf][reg]);
      }
    // gather B-fragments (same-wave rows; LDS ops are wave-ordered)
    qf[3] = *(const short8*)(sGh + qrl * 32 + l4 * 8);
    qf[4] = *(const short8*)(sGw + qrl * 32 + l4 * 8);
  }

  float m = -1e30f, lsum = 0.f;
  f32x4 acc[6];
#pragma unroll
  for (int i = 0; i < 6; ++i) acc[i] = z4;

  writeV();
  __syncthreads();   // drains K'(0) staging; sV visible; sG reads done

  for (int kt = 0; kt < 13; ++kt){
    const int cur = kt & 1;
    if (kt < 12){ loadV(kt + 1); stageK(kt + 1, cur ^ 1); }

    // ---- S'^T = mfma(K', Q'): finished log2-logits, lane holds k-rows ----
    f32x4 sfr[4] = {z4, z4, z4, z4};
#pragma unroll
    for (int ks = 0; ks < 5; ++ks){
#pragma unroll
      for (int nf = 0; nf < 4; ++nf){
        const int r = nf * 16 + l15;
        const int sl = (ks * 4 + l4) ^ (r & 3);
        const short8 kb = *(const short8*)(sK[cur] + r * 160 + sl * 8);
        sfr[nf] = mfma16(kb, qf[ks], sfr[nf]);
      }
    }
    if (kt == 12){                 // keys 784..831 invalid: frags nf>=1
      const f32x4 m30 = {-1e30f, -1e30f, -1e30f, -1e30f};
      sfr[1] = m30; sfr[2] = m30; sfr[3] = m30;
    }

    // ---- lane-local online softmax (log2 domain) ----
    float mx;
    {
      float a0 = fmaxf(fmaxf(sfr[0][0], sfr[0][1]), fmaxf(sfr[0][2], sfr[0][3]));
      float a1 = fmaxf(fmaxf(sfr[1][0], sfr[1][1]), fmaxf(sfr[1][2], sfr[1][3]));
      float a2 = fmaxf(fmaxf(sfr[2][0], sfr[2][1]), fmaxf(sfr[2][2], sfr[2][3]));
      float a3 = fmaxf(fmaxf(sfr[3][0], sfr[3][1]), fmaxf(sfr[3][2], sfr[3][3]));
      mx = fmaxf(fmaxf(a0, a1), fmaxf(a2, a3));
    }
    mx = fmaxf(mx, __shfl_xor(mx, 16));
    mx = fmaxf(mx, __shfl_xor(mx, 32));
    const float mn = fmaxf(m, mx);
    const float al = exp2f(m - mn);
    m = mn;
    float sum;
    {
#pragma unroll
      for (int nf = 0; nf < 4; ++nf)
#pragma unroll
        for (int reg = 0; reg < 4; ++reg)
          sfr[nf][reg] = exp2f(sfr[nf][reg] - mn);
      float s0 = (sfr[0][0] + sfr[0][1]) + (sfr[0][2] + sfr[0][3]);
      float s1 = (sfr[1][0] + sfr[1][1]) + (sfr[1][2] + sfr[1][3]);
      float s2 = (sfr[2][0] + sfr[2][1]) + (sfr[2][2] + sfr[2][3]);
      float s3 = (sfr[3][0] + sfr[3][1]) + (sfr[3][2] + sfr[3][3]);
      sum = (s0 + s1) + (s2 + s3);
    }
    sum += __shfl_xor(sum, 16);
    sum += __shfl_xor(sum, 32);
    lsum = lsum * al + sum;

    __syncthreads();   // B1: all QK' reads of sK[cur] done -> head free for P

    // ---- P -> sK[cur] head (per-wave-private rows, swizzled) ----
    unsigned short* sPp = sK[cur];
#pragma unroll
    for (int nf = 0; nf < 4; ++nf){
      short4v p4;
      p4[0] = (short)f2bf(sfr[nf][0]); p4[1] = (short)f2bf(sfr[nf][1]);
      p4[2] = (short)f2bf(sfr[nf][2]); p4[3] = (short)f2bf(sfr[nf][3]);
      char* dst = (char*)sPp + qrl * 128 + (((nf * 2 + (l4 >> 1)) ^ (l15 & 7)) << 4) + ((l4 & 1) << 3);
      *(short4v*)dst = p4;
    }
    // rescale O^T by per-lane alpha
#pragma unroll
    for (int i = 0; i < 6; ++i)
#pragma unroll
      for (int reg = 0; reg < 4; ++reg)
        acc[i][reg] *= al;

    // ---- O^T += mfma(V^T, P) ----
#pragma unroll
    for (int ks = 0; ks < 2; ++ks){
      const short8 pb = *(const short8*)((char*)sPp + qrl * 128 + (((ks * 4 + l4) ^ (l15 & 7)) << 4));
#pragma unroll
      for (int nf = 0; nf < 6; ++nf){
        const int r = nf * 16 + l15;
        const int sl = (ks * 4 + l4) ^ (r & 7);
        const short8 vb = *(const short8*)(sV + r * 64 + sl * 8);
        acc[nf] = mfma16(vb, pb, acc[nf]);
      }
    }

    if (kt < 12){
      __syncthreads();   // B2: PV reads of sV + P done; staging drained
      writeV();
      __syncthreads();   // B3: sV(t+1) visible
    }
  }

  // ---- epilogue: O[q][d] = O^T/lsum + residual ----
  const int qg = qb * 128 + qrl;
  if (qg < 784){
    const float rcp = 1.f / lsum;
    const float* qrow = qpf + baseq + (size_t)qg * 96;
    float* orow = out + ((size_t)b * 784 + qg) * 384 + h * 96;
#pragma unroll
    for (int nf = 0; nf < 6; ++nf)
#pragma unroll
      for (int reg = 0; reg < 4; ++reg){
        const int d = nf * 16 + l4 * 4 + reg;
        orow[d] = acc[nf][reg] * rcp + qrow[d];
      }
  }
}

// ---------------- launcher -----------------------------------------------------
extern "C" void kernel_launch(void* const* d_in, const int* in_sizes, int n_in,
                              void* d_out, int out_size, void* d_ws, size_t ws_size,
                              hipStream_t stream){
  const float* hs  = (const float*)d_in[0];
  const float* qw  = (const float*)d_in[1];
  const float* qb  = (const float*)d_in[2];
  const float* pwq = (const float*)d_in[3];
  const float* pwk = (const float*)d_in[4];
  const float* pwv = (const float*)d_in[5];
  const float* gq  = (const float*)d_in[6];
  const float* bq  = (const float*)d_in[7];
  const float* gk  = (const float*)d_in[8];
  const float* bk  = (const float*)d_in[9];
  const float* gv  = (const float*)d_in[10];
  const float* bv  = (const float*)d_in[11];
  const float* rh  = (const float*)d_in[12];
  const float* rw  = (const float*)d_in[13];
  float* out = (float*)d_out;

  char* ws = (char*)d_ws;
  size_t off = 0;
  auto take = [&](size_t n)->char*{ char* p = ws + off; off += (n + 255) & ~(size_t)255; return p; };
  unsigned short* hsb = (unsigned short*)take((size_t)50176 * 192 * 2);
  unsigned short* wtb = (unsigned short*)take((size_t)1152 * 192 * 2);
  unsigned short* qkv = (unsigned short*)take((size_t)50176 * 1152 * 2);
  unsigned short* qpb = (unsigned short*)take((size_t)64 * 784 * 96 * 2);
  unsigned short* kpb = (unsigned short*)take((size_t)64 * 784 * 160 * 2);   // extended K'
  unsigned short* vpt = (unsigned short*)take((size_t)64 * 784 * 96 * 2);
  float* qpf          = (float*)take((size_t)64 * 784 * 96 * 4);

  hipLaunchKernelGGL(k_convert, dim3(1024), dim3(256), 0, stream,
                     (const float4*)hs, qw, hsb, wtb);
  hipLaunchKernelGGL(k_gemm, dim3(392 * 9), dim3(256), 0, stream, hsb, wtb, qb, qkv);
  hipLaunchKernelGGL(k_pool_ln, dim3(5376), dim3(384), 0, stream, qkv,
                     pwq, pwk, pwv, gq, bq, gk, bk, gv, bv, qpb, kpb, vpt, qpf);
  hipLaunchKernelGGL(k_attn, dim3(448), dim3(512), 0, stream,
                     qpb, kpb, vpt, qpf, rh, rw, out);
}